// Round 10
// baseline (43.682 us; speedup 1.0000x reference)
//
#include <hip/hip_runtime.h>
#include <hip/hip_bf16.h>
#include <math.h>

// B=128, F_IN=1000, D=512, K=10, C=5, T=1000, TAU=0.1
// Contraction: logits_s[b,t,k] = sum_c v[b,c,t]*M[b,c,k], M = h @ W_mlp.
// R10: 4 nodes. vs R9: kB widened to 64-e chunks (halved r_b restage,
// d-major padded LDS = conflict-free broadcasts, float4 tile) and kCG
// covers all 1000 t per b (phase-1 gate/M computed once, not twice).
//   kA  (16 e x 20 ks) -> pA[20][128][512]           [weight-once, LDS]
//   kRA reduce 20 partials + bias + relu -> r_b
//   kB  (8 e x 8 ds x 5 c) -> pB[8][5][128][512]     [weight-once, LDS]
//   kCG per b: phase1 waves 0-4 reduce pB -> gate p[c], M[c][k];
//       phase2 two 500-t passes: gumbel-sigmoid, softmax_c, MLP, softmax_k.

// ---- adapt partials ----
__global__ __launch_bounds__(256) void kA(const float* __restrict__ feats,
                                          const float* __restrict__ W_adapt,
                                          float* __restrict__ pA) {
    __shared__ float fls[128 * 50];   // [b][k]
    __shared__ float wls[50 * 32];    // [k][e]
    const int tid = threadIdx.x;
    const int e0 = blockIdx.x * 32;
    const int s  = blockIdx.y;
    const int k0 = s * 50;

    #pragma unroll
    for (int it = 0; it < 25; ++it) {          // 6400 = 25*256
        int idx = it * 256 + tid;
        int b_l = idx / 50, k_l = idx - b_l * 50;
        fls[idx] = feats[b_l * 1000 + k0 + k_l];
    }
    #pragma unroll
    for (int it = 0; it < 7; ++it) {           // 1600 elems
        int idx = it * 256 + tid;
        if (idx < 1600)
            wls[idx] = W_adapt[(k0 + (idx >> 5)) * 512 + e0 + (idx & 31)];
    }
    __syncthreads();

    const int ep = tid & 15, bg = tid >> 4;    // 16 e-pairs x 16 b-groups
    float2 acc[8] = {};
    const float* fb = &fls[bg * 8 * 50];
    const float* wb = &wls[ep * 2];
    #pragma unroll 2
    for (int k = 0; k < 50; ++k) {
        float2 w = *(const float2*)&wb[k * 32];
        #pragma unroll
        for (int i = 0; i < 8; ++i) {
            float r = fb[i * 50 + k];          // LDS broadcast
            acc[i].x = fmaf(r, w.x, acc[i].x);
            acc[i].y = fmaf(r, w.y, acc[i].y);
        }
    }
    #pragma unroll
    for (int i = 0; i < 8; ++i)
        *(float2*)&pA[(s * 128 + bg * 8 + i) * 512 + e0 + ep * 2] = acc[i];
}

// ---- reduce 20 partials + bias + relu ----
__global__ __launch_bounds__(256) void kRA(const float* __restrict__ pA,
                                           const float* __restrict__ b_adapt,
                                           float* __restrict__ r_b) {
    int i = blockIdx.x * 256 + threadIdx.x;    // < 65536
    float acc = b_adapt[i & 511];
    #pragma unroll
    for (int s = 0; s < 20; ++s) acc += pA[s * 65536 + i];
    r_b[i] = fmaxf(acc, 0.f);
}

// ---- channel partials: pB[ds][c][b][e]; 64-e chunks, d-major padded LDS ----
__global__ __launch_bounds__(256) void kB(const float* __restrict__ r_b,
                                          const float* __restrict__ W_ch,
                                          float* __restrict__ pB) {
    __shared__ float rbs[64 * 129];   // [d][b] +1 pad: conflict-free
    __shared__ float wls[64 * 64];    // [d][e]
    const int tid = threadIdx.x;
    const int e0 = blockIdx.x * 64;   // 8 chunks
    const int ds = blockIdx.y;        // 8 d-splits
    const int c  = blockIdx.z;        // 5
    const int d0 = ds * 64;

    #pragma unroll
    for (int it = 0; it < 32; ++it) {          // 8192 = 32*256
        int idx = it * 256 + tid;              // b*64 + d
        int b = idx >> 6, d = idx & 63;
        rbs[d * 129 + b] = r_b[b * 512 + d0 + d];   // global coalesced
    }
    #pragma unroll
    for (int it = 0; it < 16; ++it) {          // 4096 = 16*256
        int idx = it * 256 + tid;              // d*64 + e
        wls[idx] = W_ch[((size_t)(c * 512 + d0 + (idx >> 6))) * 512 + e0 + (idx & 63)];
    }
    __syncthreads();

    const int ep = tid & 15, bg = tid >> 4;    // 16 e-quads x 16 b-groups
    float4 acc[8] = {};
    #pragma unroll 2
    for (int d = 0; d < 64; ++d) {
        float4 w = *(const float4*)&wls[d * 64 + ep * 4];
        const float* rr = &rbs[d * 129 + bg * 8];   // 8 contiguous b
        #pragma unroll
        for (int i = 0; i < 8; ++i) {
            float r = rr[i];
            acc[i].x = fmaf(r, w.x, acc[i].x);
            acc[i].y = fmaf(r, w.y, acc[i].y);
            acc[i].z = fmaf(r, w.z, acc[i].z);
            acc[i].w = fmaf(r, w.w, acc[i].w);
        }
    }
    #pragma unroll
    for (int i = 0; i < 8; ++i)
        *(float4*)&pB[((ds * 5 + c) * 128 + bg * 8 + i) * 512 + e0 + ep * 4] = acc[i];
}

// ---- fused gate/M + epilogue: one block per b, 512 thr ----
__global__ __launch_bounds__(512) void kCG(const float* __restrict__ pB,
                                           const float* __restrict__ b_ch,
                                           const float* __restrict__ W_gate,
                                           const float* __restrict__ W_mlp,
                                           const float* __restrict__ b_gate,
                                           const float* __restrict__ b_mlp,
                                           const float* __restrict__ gumbel,
                                           float* __restrict__ out_rs,
                                           float* __restrict__ out_gt,
                                           float* __restrict__ out_pt) {
    __shared__ float sWm[5120];        // W_mlp [e][k]
    __shared__ float red[5][11];
    __shared__ float spv[5], sM[50];
    const int tid = threadIdx.x;
    const int b = blockIdx.x;

    #pragma unroll
    for (int it = 0; it < 10; ++it) sWm[it * 512 + tid] = W_mlp[it * 512 + tid];
    __syncthreads();

    // phase 1: wave c (0-4) computes gate + M for channel c (reduce 8 partials)
    const int wv = tid >> 6, lane = tid & 63;
    if (wv < 5) {
        const int c = wv;
        float gs = 0.f, am[10] = {};
        #pragma unroll
        for (int i = 0; i < 8; ++i) {
            int e = i * 64 + lane;
            float hs = b_ch[c * 512 + e];
            #pragma unroll
            for (int s = 0; s < 8; ++s)
                hs += pB[((s * 5 + c) * 128 + b) * 512 + e];
            float h = fmaxf(hs, 0.f);
            gs = fmaf(h, W_gate[c * 512 + e], gs);
            const float* wm = &sWm[e * 10];
            #pragma unroll
            for (int k = 0; k < 10; ++k) am[k] = fmaf(h, wm[k], am[k]);
        }
        #pragma unroll
        for (int off = 32; off; off >>= 1) {
            gs += __shfl_xor(gs, off);
            #pragma unroll
            for (int k = 0; k < 10; ++k) am[k] += __shfl_xor(am[k], off);
        }
        if (lane == 0) {
            red[c][0] = gs;
            #pragma unroll
            for (int k = 0; k < 10; ++k) red[c][1 + k] = am[k];
        }
    }
    __syncthreads();
    if (tid < 5) {
        float pv = 1.f / (1.f + __expf(-(red[tid][0] + b_gate[tid])));
        spv[tid] = pv;
        out_pt[b * 5 + tid] = pv;
    }
    if (tid < 50) sM[tid] = red[tid / 10][1 + tid % 10];
    __syncthreads();

    // phase 2: two 500-t passes
    #pragma unroll
    for (int rep = 0; rep < 2; ++rep) {
        if (tid < 500) {
            int t = rep * 500 + tid;
            float ex[5], ssum = 0.f;
            #pragma unroll
            for (int c = 0; c < 5; ++c) {
                float2 gu = *(const float2*)&gumbel[(size_t)(((b * 5 + c) * 1000) + t) * 2];
                float arg = (2.f * spv[c] - 1.f + gu.y - gu.x) * 10.0f;  // /tau
                float gt  = 1.f / (1.f + __expf(-arg));
                out_gt[(b * 5 + c) * 1000 + t] = gt;
                float e = __expf(gt);
                ex[c] = e; ssum += e;
            }
            float inv = 1.f / ssum;
            float lg[10];
            #pragma unroll
            for (int k = 0; k < 10; ++k) lg[k] = b_mlp[k];
            #pragma unroll
            for (int c = 0; c < 5; ++c) {
                float v = ex[c] * inv;
                #pragma unroll
                for (int k = 0; k < 10; ++k) lg[k] = fmaf(v, sM[c * 10 + k], lg[k]);
            }
            float mx = 0.f;
            #pragma unroll
            for (int k = 0; k < 10; ++k) { lg[k] = fmaxf(lg[k], 0.f); mx = fmaxf(mx, lg[k]); }
            float se = 0.f;
            #pragma unroll
            for (int k = 0; k < 10; ++k) { lg[k] = __expf(lg[k] - mx); se += lg[k]; }
            float invs = 1.f / se;
            float2 outv[5];
            #pragma unroll
            for (int k = 0; k < 10; ++k) ((float*)outv)[k] = lg[k] * invs;
            float2* dst = (float2*)&out_rs[(size_t)t * 1280 + b * 10];
            #pragma unroll
            for (int j = 0; j < 5; ++j) dst[j] = outv[j];
        }
    }
}

extern "C" void kernel_launch(void* const* d_in, const int* in_sizes, int n_in,
                              void* d_out, int out_size, void* d_ws, size_t ws_size,
                              hipStream_t stream) {
    const float* feats   = (const float*)d_in[0];
    const float* W_adapt = (const float*)d_in[1];
    const float* b_adapt = (const float*)d_in[2];
    const float* W_ch    = (const float*)d_in[3];
    const float* b_ch    = (const float*)d_in[4];
    const float* W_gate  = (const float*)d_in[5];
    const float* b_gate  = (const float*)d_in[6];
    const float* W_mlp   = (const float*)d_in[7];
    const float* b_mlp   = (const float*)d_in[8];
    const float* gumbel  = (const float*)d_in[9];

    float* out    = (float*)d_out;
    float* out_rs = out;                  // (T,B,K)  1,280,000
    float* out_gt = out + 1280000;        // (B,C,T)    640,000
    float* out_pt = out + 1920000;        // (B,C,1)        640

    float* ws  = (float*)d_ws;
    float* pA  = ws;                      // 20*128*512  = 1,310,720
    float* pB  = pA + 1310720;            // 8*5*128*512 = 2,621,440
    float* r_b = pB + 2621440;            //    65,536

    kA <<<dim3(16, 20),  256, 0, stream>>>(feats, W_adapt, pA);
    kRA<<<256,           256, 0, stream>>>(pA, b_adapt, r_b);
    kB <<<dim3(8, 8, 5), 256, 0, stream>>>(r_b, W_ch, pB);
    kCG<<<128,           512, 0, stream>>>(pB, b_ch, W_gate, W_mlp, b_gate,
                                           b_mlp, gumbel, out_rs, out_gt, out_pt);
}

// Round 11
// 41.712 us; speedup vs baseline: 1.0472x; 1.0472x over previous
//
#include <hip/hip_runtime.h>
#include <hip/hip_bf16.h>
#include <math.h>

// B=128, F_IN=1000, D=512, K=10, C=5, T=1000, TAU=0.1
// Contraction: logits_s[b,t,k] = sum_c v[b,c,t]*M[b,c,k], M = h @ W_mlp.
// R11: 4 nodes. R9 base (best, 42.1us) with kB's LDS made conflict-free
// at UNCHANGED 640-block occupancy (R10 regression was occupancy loss,
// not the pad): rbs [d][132] pad, rr via 2x ds_read_b128, w float2.
//   kA  (16 e x 20 ks) -> pA[20][128][512]           [weight-once, LDS]
//   kRA reduce 20 partials + bias + relu -> r_b
//   kB  (16 e x 8 ds x 5 c) -> pB[8][5][128][512]    [weight-once, LDS]
//   kCG grid(2 tc,128 b): phase1 waves 0-4 reduce pB -> gate p[c], M[c][k]
//       (dup x2); phase2 per-t gumbel-sigmoid, softmax_c, MLP, softmax_k.

// ---- adapt partials ----
__global__ __launch_bounds__(256) void kA(const float* __restrict__ feats,
                                          const float* __restrict__ W_adapt,
                                          float* __restrict__ pA) {
    __shared__ float fls[128 * 50];   // [b][k]
    __shared__ float wls[50 * 32];    // [k][e]
    const int tid = threadIdx.x;
    const int e0 = blockIdx.x * 32;
    const int s  = blockIdx.y;
    const int k0 = s * 50;

    #pragma unroll
    for (int it = 0; it < 25; ++it) {          // 6400 = 25*256
        int idx = it * 256 + tid;
        int b_l = idx / 50, k_l = idx - b_l * 50;
        fls[idx] = feats[b_l * 1000 + k0 + k_l];
    }
    #pragma unroll
    for (int it = 0; it < 7; ++it) {           // 1600 elems
        int idx = it * 256 + tid;
        if (idx < 1600)
            wls[idx] = W_adapt[(k0 + (idx >> 5)) * 512 + e0 + (idx & 31)];
    }
    __syncthreads();

    const int ep = tid & 15, bg = tid >> 4;    // 16 e-pairs x 16 b-groups
    float2 acc[8] = {};
    const float* fb = &fls[bg * 8 * 50];
    const float* wb = &wls[ep * 2];
    #pragma unroll 2
    for (int k = 0; k < 50; ++k) {
        float2 w = *(const float2*)&wb[k * 32];
        #pragma unroll
        for (int i = 0; i < 8; ++i) {
            float r = fb[i * 50 + k];          // LDS broadcast
            acc[i].x = fmaf(r, w.x, acc[i].x);
            acc[i].y = fmaf(r, w.y, acc[i].y);
        }
    }
    #pragma unroll
    for (int i = 0; i < 8; ++i)
        *(float2*)&pA[(s * 128 + bg * 8 + i) * 512 + e0 + ep * 2] = acc[i];
}

// ---- reduce 20 partials + bias + relu ----
__global__ __launch_bounds__(256) void kRA(const float* __restrict__ pA,
                                           const float* __restrict__ b_adapt,
                                           float* __restrict__ r_b) {
    int i = blockIdx.x * 256 + threadIdx.x;    // < 65536
    float acc = b_adapt[i & 511];
    #pragma unroll
    for (int s = 0; s < 20; ++s) acc += pA[s * 65536 + i];
    r_b[i] = fmaxf(acc, 0.f);
}

// ---- channel partials: pB[ds][c][b][e]; 640 blocks, conflict-free LDS ----
#define RBP 132   // pad: banks of rbs[d*RBP + b] spread, b128-aligned
__global__ __launch_bounds__(256) void kB(const float* __restrict__ r_b,
                                          const float* __restrict__ W_ch,
                                          float* __restrict__ pB) {
    __shared__ float rbs[64 * RBP];   // [d][b], 33.8 KB
    __shared__ float wls[64 * 32];    // [d][e], 8 KB
    const int tid = threadIdx.x;
    const int e0 = blockIdx.x * 32;   // 16 chunks
    const int ds = blockIdx.y;        // 8 d-splits
    const int c  = blockIdx.z;        // 5
    const int d0 = ds * 64;

    // stage r_b slice: float4 global loads (coalesced), scalar LDS writes
    #pragma unroll
    for (int it = 0; it < 8; ++it) {           // 2048 float4 = 64d x 128b
        int idx = it * 256 + tid;
        int b = idx >> 4, q = idx & 15;        // q: d-quad
        float4 v = *(const float4*)&r_b[b * 512 + d0 + q * 4];
        rbs[(q * 4 + 0) * RBP + b] = v.x;
        rbs[(q * 4 + 1) * RBP + b] = v.y;
        rbs[(q * 4 + 2) * RBP + b] = v.z;
        rbs[(q * 4 + 3) * RBP + b] = v.w;
    }
    #pragma unroll
    for (int it = 0; it < 8; ++it) {           // 2048 = 64d x 32e
        int idx = it * 256 + tid;
        wls[idx] = W_ch[((size_t)(c * 512 + d0 + (idx >> 5))) * 512 + e0 + (idx & 31)];
    }
    __syncthreads();

    const int ep = tid & 15, bg = tid >> 4;    // 16 e-pairs x 16 b-groups
    float2 acc[8] = {};
    #pragma unroll 2
    for (int d = 0; d < 64; ++d) {
        float2 w = *(const float2*)&wls[d * 32 + ep * 2];
        float4 r0 = *(const float4*)&rbs[d * RBP + bg * 8];      // b128, cf
        float4 r1 = *(const float4*)&rbs[d * RBP + bg * 8 + 4];  // b128, cf
        acc[0].x = fmaf(r0.x, w.x, acc[0].x); acc[0].y = fmaf(r0.x, w.y, acc[0].y);
        acc[1].x = fmaf(r0.y, w.x, acc[1].x); acc[1].y = fmaf(r0.y, w.y, acc[1].y);
        acc[2].x = fmaf(r0.z, w.x, acc[2].x); acc[2].y = fmaf(r0.z, w.y, acc[2].y);
        acc[3].x = fmaf(r0.w, w.x, acc[3].x); acc[3].y = fmaf(r0.w, w.y, acc[3].y);
        acc[4].x = fmaf(r1.x, w.x, acc[4].x); acc[4].y = fmaf(r1.x, w.y, acc[4].y);
        acc[5].x = fmaf(r1.y, w.x, acc[5].x); acc[5].y = fmaf(r1.y, w.y, acc[5].y);
        acc[6].x = fmaf(r1.z, w.x, acc[6].x); acc[6].y = fmaf(r1.z, w.y, acc[6].y);
        acc[7].x = fmaf(r1.w, w.x, acc[7].x); acc[7].y = fmaf(r1.w, w.y, acc[7].y);
    }
    #pragma unroll
    for (int i = 0; i < 8; ++i)
        *(float2*)&pB[((ds * 5 + c) * 128 + bg * 8 + i) * 512 + e0 + ep * 2] = acc[i];
}

// ---- fused gate/M + epilogue: grid (2 tc, 128 b) x 512 thr ----
__global__ __launch_bounds__(512) void kCG(const float* __restrict__ pB,
                                           const float* __restrict__ b_ch,
                                           const float* __restrict__ W_gate,
                                           const float* __restrict__ W_mlp,
                                           const float* __restrict__ b_gate,
                                           const float* __restrict__ b_mlp,
                                           const float* __restrict__ gumbel,
                                           float* __restrict__ out_rs,
                                           float* __restrict__ out_gt,
                                           float* __restrict__ out_pt) {
    __shared__ float sWm[5120];        // W_mlp [e][k]
    __shared__ float red[5][11];
    __shared__ float spv[5], sM[50];
    const int tid = threadIdx.x;
    const int tc = blockIdx.x, b = blockIdx.y;

    #pragma unroll
    for (int it = 0; it < 10; ++it) sWm[it * 512 + tid] = W_mlp[it * 512 + tid];
    __syncthreads();

    // phase 1: wave c (0-4) computes gate + M for channel c (reduce 8 partials)
    const int wv = tid >> 6, lane = tid & 63;
    if (wv < 5) {
        const int c = wv;
        float gs = 0.f, am[10] = {};
        #pragma unroll
        for (int i = 0; i < 8; ++i) {
            int e = i * 64 + lane;
            float hs = b_ch[c * 512 + e];
            #pragma unroll
            for (int s = 0; s < 8; ++s)
                hs += pB[((s * 5 + c) * 128 + b) * 512 + e];
            float h = fmaxf(hs, 0.f);
            gs = fmaf(h, W_gate[c * 512 + e], gs);
            const float* wm = &sWm[e * 10];
            #pragma unroll
            for (int k = 0; k < 10; ++k) am[k] = fmaf(h, wm[k], am[k]);
        }
        #pragma unroll
        for (int off = 32; off; off >>= 1) {
            gs += __shfl_xor(gs, off);
            #pragma unroll
            for (int k = 0; k < 10; ++k) am[k] += __shfl_xor(am[k], off);
        }
        if (lane == 0) {
            red[c][0] = gs;
            #pragma unroll
            for (int k = 0; k < 10; ++k) red[c][1 + k] = am[k];
        }
    }
    __syncthreads();
    if (tid < 5) {
        float pv = 1.f / (1.f + __expf(-(red[tid][0] + b_gate[tid])));
        spv[tid] = pv;
        if (tc == 0) out_pt[b * 5 + tid] = pv;
    }
    if (tid < 50) sM[tid] = red[tid / 10][1 + tid % 10];
    __syncthreads();

    // phase 2: epilogue, 500 t per block
    int t = tc * 500 + tid;
    if (tid >= 500) return;
    float ex[5], ssum = 0.f;
    #pragma unroll
    for (int c = 0; c < 5; ++c) {
        float2 gu = *(const float2*)&gumbel[(size_t)(((b * 5 + c) * 1000) + t) * 2];
        float arg = (2.f * spv[c] - 1.f + gu.y - gu.x) * 10.0f;  // /tau
        float gt  = 1.f / (1.f + __expf(-arg));
        out_gt[(b * 5 + c) * 1000 + t] = gt;
        float e = __expf(gt);
        ex[c] = e; ssum += e;
    }
    float inv = 1.f / ssum;
    float lg[10];
    #pragma unroll
    for (int k = 0; k < 10; ++k) lg[k] = b_mlp[k];
    #pragma unroll
    for (int c = 0; c < 5; ++c) {
        float v = ex[c] * inv;
        #pragma unroll
        for (int k = 0; k < 10; ++k) lg[k] = fmaf(v, sM[c * 10 + k], lg[k]);
    }
    float mx = 0.f;
    #pragma unroll
    for (int k = 0; k < 10; ++k) { lg[k] = fmaxf(lg[k], 0.f); mx = fmaxf(mx, lg[k]); }
    float se = 0.f;
    #pragma unroll
    for (int k = 0; k < 10; ++k) { lg[k] = __expf(lg[k] - mx); se += lg[k]; }
    float invs = 1.f / se;
    float2 outv[5];
    #pragma unroll
    for (int k = 0; k < 10; ++k) ((float*)outv)[k] = lg[k] * invs;
    float2* dst = (float2*)&out_rs[(size_t)t * 1280 + b * 10];
    #pragma unroll
    for (int j = 0; j < 5; ++j) dst[j] = outv[j];
}

extern "C" void kernel_launch(void* const* d_in, const int* in_sizes, int n_in,
                              void* d_out, int out_size, void* d_ws, size_t ws_size,
                              hipStream_t stream) {
    const float* feats   = (const float*)d_in[0];
    const float* W_adapt = (const float*)d_in[1];
    const float* b_adapt = (const float*)d_in[2];
    const float* W_ch    = (const float*)d_in[3];
    const float* b_ch    = (const float*)d_in[4];
    const float* W_gate  = (const float*)d_in[5];
    const float* b_gate  = (const float*)d_in[6];
    const float* W_mlp   = (const float*)d_in[7];
    const float* b_mlp   = (const float*)d_in[8];
    const float* gumbel  = (const float*)d_in[9];

    float* out    = (float*)d_out;
    float* out_rs = out;                  // (T,B,K)  1,280,000
    float* out_gt = out + 1280000;        // (B,C,T)    640,000
    float* out_pt = out + 1920000;        // (B,C,1)        640

    float* ws  = (float*)d_ws;
    float* pA  = ws;                      // 20*128*512  = 1,310,720
    float* pB  = pA + 1310720;            // 8*5*128*512 = 2,621,440
    float* r_b = pB + 2621440;            //    65,536

    kA <<<dim3(16, 20),   256, 0, stream>>>(feats, W_adapt, pA);
    kRA<<<256,            256, 0, stream>>>(pA, b_adapt, r_b);
    kB <<<dim3(16, 8, 5), 256, 0, stream>>>(r_b, W_ch, pB);
    kCG<<<dim3(2, 128),   512, 0, stream>>>(pB, b_ch, W_gate, W_mlp, b_gate,
                                            b_mlp, gumbel, out_rs, out_gt, out_pt);
}